// Round 1
// baseline (925.285 us; speedup 1.0000x reference)
//
#include <hip/hip_runtime.h>
#include <math.h>
#include <limits.h>

#define M_ROWS 65536   // B*N = 64*1024
#define DD     256     // feature dim
#define KC     512     // codes
#define TILE_M 128
#define CHUNK  64
#define KS     64      // k-slice staged in LDS

// numpy-style pairwise sum (8 accumulators, block 128) of squares of 128 floats.
// Matches np's (x*x).sum(-1) rounding: product rounded first, then pairwise adds.
__device__ __forceinline__ float pw128_sq(const float4* __restrict__ q) {
  float r[8];
  {
    float4 a = q[0], b = q[1];
    r[0] = __fmul_rn(a.x, a.x); r[1] = __fmul_rn(a.y, a.y);
    r[2] = __fmul_rn(a.z, a.z); r[3] = __fmul_rn(a.w, a.w);
    r[4] = __fmul_rn(b.x, b.x); r[5] = __fmul_rn(b.y, b.y);
    r[6] = __fmul_rn(b.z, b.z); r[7] = __fmul_rn(b.w, b.w);
  }
#pragma unroll
  for (int i = 2; i < 32; i += 2) {
    float4 a = q[i], b = q[i + 1];
    r[0] = __fadd_rn(r[0], __fmul_rn(a.x, a.x));
    r[1] = __fadd_rn(r[1], __fmul_rn(a.y, a.y));
    r[2] = __fadd_rn(r[2], __fmul_rn(a.z, a.z));
    r[3] = __fadd_rn(r[3], __fmul_rn(a.w, a.w));
    r[4] = __fadd_rn(r[4], __fmul_rn(b.x, b.x));
    r[5] = __fadd_rn(r[5], __fmul_rn(b.y, b.y));
    r[6] = __fadd_rn(r[6], __fmul_rn(b.z, b.z));
    r[7] = __fadd_rn(r[7], __fmul_rn(b.w, b.w));
  }
  return __fadd_rn(__fadd_rn(__fadd_rn(r[0], r[1]), __fadd_rn(r[2], r[3])),
                   __fadd_rn(__fadd_rn(r[4], r[5]), __fadd_rn(r[6], r[7])));
}

// s[r] = numpy pairwise sum of row r squared (n=256 splits 128+128)
__global__ void sumsq_kernel(const float* __restrict__ x, float* __restrict__ s,
                             int nrows) {
  int r = blockIdx.x * blockDim.x + threadIdx.x;
  if (r >= nrows) return;
  const float4* q = (const float4*)(x + (size_t)r * DD);
  s[r] = __fadd_rn(pw128_sq(q), pw128_sq(q + 32));
}

__global__ __launch_bounds__(256) void vq_kernel(
    const float* __restrict__ z, const float* __restrict__ cb,
    const float* __restrict__ s, const float* __restrict__ se,
    float* __restrict__ out) {
  __shared__ float zs[TILE_M][KS];   // 32 KB
  __shared__ float es[CHUNK][KS];    // 16 KB
  __shared__ float s_l[TILE_M];
  __shared__ float se_l[KC];
  __shared__ int   best_l[TILE_M];

  const int tid = threadIdx.x;
  const int tx = tid & 15, ty = tid >> 4;
  const int r0 = blockIdx.x * TILE_M;

  if (tid < TILE_M) s_l[tid] = s[r0 + tid];
  se_l[tid] = se[tid];
  se_l[tid + 256] = se[tid + 256];
  // first __syncthreads below (top of ks loop) publishes these

  float bestd[8];
  int   besti[8];
#pragma unroll
  for (int i = 0; i < 8; ++i) { bestd[i] = INFINITY; besti[i] = INT_MAX; }

  const float4* zg = (const float4*)z;
  const float4* cg = (const float4*)cb;
  float4* zs4 = (float4*)zs;
  float4* es4 = (float4*)es;

  for (int ch = 0; ch < KC / CHUNK; ++ch) {
    const int cbase = ch * CHUNK;
    float acc[8][4];
#pragma unroll
    for (int i = 0; i < 8; ++i)
#pragma unroll
      for (int j = 0; j < 4; ++j) acc[i][j] = 0.0f;

    for (int ks = 0; ks < DD / KS; ++ks) {
      __syncthreads();  // LDS reuse barrier (also publishes prologue on iter 0)
      // stage z slice: 128 rows x 16 float4
#pragma unroll
      for (int p = 0; p < 8; ++p) {
        int u = p * 256 + tid;
        int row = u >> 4, c4 = u & 15;
        zs4[u] = zg[(size_t)(r0 + row) * 64 + ks * 16 + c4];
      }
      // stage e slice: 64 codes x 16 float4
#pragma unroll
      for (int p = 0; p < 4; ++p) {
        int u = p * 256 + tid;
        int crow = u >> 4, c4 = u & 15;
        es4[u] = cg[(size_t)(cbase + crow) * 64 + ks * 16 + c4];
      }
      __syncthreads();

#pragma unroll
      for (int k4 = 0; k4 < 16; ++k4) {
        float4 zf[8], ef[4];
#pragma unroll
        for (int i = 0; i < 8; ++i) zf[i] = zs4[(ty * 8 + i) * 16 + k4];
#pragma unroll
        for (int j = 0; j < 4; ++j) ef[j] = es4[(tx * 4 + j) * 16 + k4];
        // strict k-ascending FMA chain per (row, code): matches BLAS microkernel
#pragma unroll
        for (int i = 0; i < 8; ++i)
#pragma unroll
          for (int j = 0; j < 4; ++j) {
            acc[i][j] = __fmaf_rn(zf[i].x, ef[j].x, acc[i][j]);
            acc[i][j] = __fmaf_rn(zf[i].y, ef[j].y, acc[i][j]);
            acc[i][j] = __fmaf_rn(zf[i].z, ef[j].z, acc[i][j]);
            acc[i][j] = __fmaf_rn(zf[i].w, ef[j].w, acc[i][j]);
          }
      }
    }

    // d = (s - 2*dot) + se, rounded exactly like the reference expression
#pragma unroll
    for (int i = 0; i < 8; ++i) {
      float s_r = s_l[ty * 8 + i];
#pragma unroll
      for (int j = 0; j < 4; ++j) {
        int code = cbase + tx * 4 + j;
        float d = __fadd_rn(__fsub_rn(s_r, __fmul_rn(2.0f, acc[i][j])),
                            se_l[code]);
        if (d < bestd[i] || (d == bestd[i] && code < besti[i])) {
          bestd[i] = d; besti[i] = code;
        }
      }
    }
  }

  // argmin reduce across the 16 tx lanes (same wave), min-d then min-index
#pragma unroll
  for (int i = 0; i < 8; ++i) {
    float bd = bestd[i];
    int   bi = besti[i];
#pragma unroll
    for (int off = 1; off < 16; off <<= 1) {
      float od = __shfl_xor(bd, off, 64);
      int   oi = __shfl_xor(bi, off, 64);
      if (od < bd || (od == bd && oi < bi)) { bd = od; bi = oi; }
    }
    if (tx == 0) best_l[ty * 8 + i] = bi;
  }
  __syncthreads();

  // epilogue: out0 = fl(z + fl(cb[idx]-z)), out1 = cb[idx]
  float4* out0 = (float4*)out;
  float4* out1 = (float4*)(out + (size_t)M_ROWS * DD);
#pragma unroll
  for (int it = 0; it < (TILE_M * 64) / 256; ++it) {
    int u = it * 256 + tid;
    int row = u >> 6, c4 = u & 63;
    size_t gidx = (size_t)(r0 + row) * 64 + c4;
    float4 zv = zg[gidx];
    float4 cv = cg[(size_t)best_l[row] * 64 + c4];
    float4 o0;
    o0.x = __fadd_rn(zv.x, __fsub_rn(cv.x, zv.x));
    o0.y = __fadd_rn(zv.y, __fsub_rn(cv.y, zv.y));
    o0.z = __fadd_rn(zv.z, __fsub_rn(cv.z, zv.z));
    o0.w = __fadd_rn(zv.w, __fsub_rn(cv.w, zv.w));
    out0[gidx] = o0;
    out1[gidx] = cv;
  }
}

extern "C" void kernel_launch(void* const* d_in, const int* in_sizes, int n_in,
                              void* d_out, int out_size, void* d_ws, size_t ws_size,
                              hipStream_t stream) {
  const float* z  = (const float*)d_in[0];   // [65536, 256]
  const float* cb = (const float*)d_in[1];   // [512, 256]
  float* out = (float*)d_out;                // 2 x [65536, 256] concat
  float* s  = (float*)d_ws;                  // ||z||^2 per row
  float* se = s + M_ROWS;                    // ||e||^2 per code

  sumsq_kernel<<<M_ROWS / 256, 256, 0, stream>>>(z, s, M_ROWS);
  sumsq_kernel<<<KC / 256, 256, 0, stream>>>(cb, se, KC);
  vq_kernel<<<M_ROWS / TILE_M, 256, 0, stream>>>(z, cb, s, se, out);
}

// Round 2
// 274.735 us; speedup vs baseline: 3.3679x; 3.3679x over previous
//
#include <hip/hip_runtime.h>
#include <math.h>
#include <limits.h>

#define M_ROWS 65536   // B*N = 64*1024
#define DD     256     // feature dim
#define KC     512     // codes
#define TILE_M 128     // rows per block
#define CHUNK  128     // codes per chunk
#define KS     32      // k-slice staged in LDS

// numpy-style pairwise sum (8 accumulators, block 128) of squares of 128 floats.
__device__ __forceinline__ float pw128_sq(const float4* __restrict__ q) {
  float r[8];
  {
    float4 a = q[0], b = q[1];
    r[0] = __fmul_rn(a.x, a.x); r[1] = __fmul_rn(a.y, a.y);
    r[2] = __fmul_rn(a.z, a.z); r[3] = __fmul_rn(a.w, a.w);
    r[4] = __fmul_rn(b.x, b.x); r[5] = __fmul_rn(b.y, b.y);
    r[6] = __fmul_rn(b.z, b.z); r[7] = __fmul_rn(b.w, b.w);
  }
#pragma unroll
  for (int i = 2; i < 32; i += 2) {
    float4 a = q[i], b = q[i + 1];
    r[0] = __fadd_rn(r[0], __fmul_rn(a.x, a.x));
    r[1] = __fadd_rn(r[1], __fmul_rn(a.y, a.y));
    r[2] = __fadd_rn(r[2], __fmul_rn(a.z, a.z));
    r[3] = __fadd_rn(r[3], __fmul_rn(a.w, a.w));
    r[4] = __fadd_rn(r[4], __fmul_rn(b.x, b.x));
    r[5] = __fadd_rn(r[5], __fmul_rn(b.y, b.y));
    r[6] = __fadd_rn(r[6], __fmul_rn(b.z, b.z));
    r[7] = __fadd_rn(r[7], __fmul_rn(b.w, b.w));
  }
  return __fadd_rn(__fadd_rn(__fadd_rn(r[0], r[1]), __fadd_rn(r[2], r[3])),
                   __fadd_rn(__fadd_rn(r[4], r[5]), __fadd_rn(r[6], r[7])));
}

__global__ void sumsq_kernel(const float* __restrict__ x, float* __restrict__ s,
                             int nrows) {
  int r = blockIdx.x * blockDim.x + threadIdx.x;
  if (r >= nrows) return;
  const float4* q = (const float4*)(x + (size_t)r * DD);
  s[r] = __fadd_rn(pw128_sq(q), pw128_sq(q + 32));
}

// LDS swizzle: float4-column q of row r stored at slot (q ^ ((r>>3)&7)).
// zf reads (rows ty*8+i, fixed k4): XOR term ty&7 -> 4 distinct bank groups/wave.
// ef reads (codes tx*8+j, fixed k4): XOR term tx&7 -> 8 groups x 2 lanes = free.
__global__ __launch_bounds__(256) void vq_kernel(
    const float* __restrict__ z, const float* __restrict__ cb,
    const float* __restrict__ s, const float* __restrict__ se,
    float* __restrict__ out) {
  __shared__ float4 zs4[TILE_M * 8];   // 16 KB  (128 rows x 32 floats, swizzled)
  __shared__ float4 es4[CHUNK * 8];    // 16 KB  (128 codes x 32 floats, swizzled)
  __shared__ float s_l[TILE_M];
  __shared__ float se_l[KC];
  __shared__ int   best_l[TILE_M];

  const int tid = threadIdx.x;
  const int tx = tid & 15, ty = tid >> 4;
  const int txs = tx & 7, tys = ty & 7;
  const int r0 = blockIdx.x * TILE_M;

  if (tid < TILE_M) s_l[tid] = s[r0 + tid];
  se_l[tid] = se[tid];
  se_l[tid + 256] = se[tid + 256];
  // published by the first __syncthreads at the top of the ks loop

  float bestd[8];
  int   besti[8];
#pragma unroll
  for (int i = 0; i < 8; ++i) { bestd[i] = INFINITY; besti[i] = INT_MAX; }

  const float4* zg = (const float4*)z;
  const float4* cg = (const float4*)cb;

  for (int ch = 0; ch < KC / CHUNK; ++ch) {   // 4 chunks of 128 codes
    const int cbase = ch * CHUNK;
    float acc[8][8];
#pragma unroll
    for (int i = 0; i < 8; ++i)
#pragma unroll
      for (int j = 0; j < 8; ++j) acc[i][j] = 0.0f;

    for (int ks = 0; ks < DD / KS; ++ks) {    // 8 k-slices of 32
      __syncthreads();  // LDS reuse barrier (publishes prologue on iter 0)
      // stage z slice: 128 rows x 8 float4, swizzled
#pragma unroll
      for (int p = 0; p < 4; ++p) {
        int u = p * 256 + tid;
        int row = u >> 3, q = u & 7;
        zs4[(row << 3) | (q ^ ((row >> 3) & 7))] =
            zg[(size_t)(r0 + row) * 64 + ks * 8 + q];
      }
      // stage e slice: 128 codes x 8 float4, swizzled
#pragma unroll
      for (int p = 0; p < 4; ++p) {
        int u = p * 256 + tid;
        int crow = u >> 3, q = u & 7;
        es4[(crow << 3) | (q ^ ((crow >> 3) & 7))] =
            cg[(size_t)(cbase + crow) * 64 + ks * 8 + q];
      }
      __syncthreads();

#pragma unroll
      for (int k4 = 0; k4 < 8; ++k4) {
        const int kz = k4 ^ tys;
        const int ke = k4 ^ txs;
        float4 zf[8];
#pragma unroll
        for (int i = 0; i < 8; ++i) zf[i] = zs4[((ty * 8 + i) << 3) | kz];
#pragma unroll
        for (int j = 0; j < 8; ++j) {
          float4 ef = es4[((tx * 8 + j) << 3) | ke];
          // strict k-ascending FMA chain per (row, code) — bit-identical to ref
#pragma unroll
          for (int i = 0; i < 8; ++i) {
            acc[i][j] = __fmaf_rn(zf[i].x, ef.x, acc[i][j]);
            acc[i][j] = __fmaf_rn(zf[i].y, ef.y, acc[i][j]);
            acc[i][j] = __fmaf_rn(zf[i].z, ef.z, acc[i][j]);
            acc[i][j] = __fmaf_rn(zf[i].w, ef.w, acc[i][j]);
          }
        }
      }
    }

    // d = (s - 2*dot) + se, rounded exactly like the reference expression
#pragma unroll
    for (int i = 0; i < 8; ++i) {
      float s_r = s_l[ty * 8 + i];
#pragma unroll
      for (int j = 0; j < 8; ++j) {
        int code = cbase + tx * 8 + j;
        float d = __fadd_rn(__fsub_rn(s_r, __fmul_rn(2.0f, acc[i][j])),
                            se_l[code]);
        if (d < bestd[i] || (d == bestd[i] && code < besti[i])) {
          bestd[i] = d; besti[i] = code;
        }
      }
    }
  }

  // argmin reduce across the 16 tx lanes (same wave), min-d then min-index
#pragma unroll
  for (int i = 0; i < 8; ++i) {
    float bd = bestd[i];
    int   bi = besti[i];
#pragma unroll
    for (int off = 1; off < 16; off <<= 1) {
      float od = __shfl_xor(bd, off, 64);
      int   oi = __shfl_xor(bi, off, 64);
      if (od < bd || (od == bd && oi < bi)) { bd = od; bi = oi; }
    }
    if (tx == 0) best_l[ty * 8 + i] = bi;
  }
  __syncthreads();

  // epilogue: out0 = fl(z + fl(cb[idx]-z)), out1 = cb[idx]
  float4* out0 = (float4*)out;
  float4* out1 = (float4*)(out + (size_t)M_ROWS * DD);
#pragma unroll
  for (int it = 0; it < (TILE_M * 64) / 256; ++it) {
    int u = it * 256 + tid;
    int row = u >> 6, c4 = u & 63;
    size_t gidx = (size_t)(r0 + row) * 64 + c4;
    float4 zv = zg[gidx];
    float4 cv = cg[(size_t)best_l[row] * 64 + c4];
    float4 o0;
    o0.x = __fadd_rn(zv.x, __fsub_rn(cv.x, zv.x));
    o0.y = __fadd_rn(zv.y, __fsub_rn(cv.y, zv.y));
    o0.z = __fadd_rn(zv.z, __fsub_rn(cv.z, zv.z));
    o0.w = __fadd_rn(zv.w, __fsub_rn(cv.w, zv.w));
    out0[gidx] = o0;
    out1[gidx] = cv;
  }
}

extern "C" void kernel_launch(void* const* d_in, const int* in_sizes, int n_in,
                              void* d_out, int out_size, void* d_ws, size_t ws_size,
                              hipStream_t stream) {
  const float* z  = (const float*)d_in[0];   // [65536, 256]
  const float* cb = (const float*)d_in[1];   // [512, 256]
  float* out = (float*)d_out;                // 2 x [65536, 256] concat
  float* s  = (float*)d_ws;                  // ||z||^2 per row
  float* se = s + M_ROWS;                    // ||e||^2 per code

  sumsq_kernel<<<M_ROWS / 256, 256, 0, stream>>>(z, s, M_ROWS);
  sumsq_kernel<<<KC / 256, 256, 0, stream>>>(cb, se, KC);
  vq_kernel<<<M_ROWS / TILE_M, 256, 0, stream>>>(z, cb, s, se, out);
}